// Round 5
// baseline (296.219 us; speedup 1.0000x reference)
//
#include <hip/hip_runtime.h>

#define B_   16
#define CIN  32
#define COUT 32
#define HH   256
#define WW   256
#define NE   8
#define NTAP 9
#define KTOT (NTAP * CIN)   // 288

#define TW 32
#define TH 8
#define NSTEP 8             // y-steps per block; chunk = 64 rows
#define CHROWS (TH * NSTEP)
#define LCOLS (TW + 2)      // 34
#define PXS   40            // ushorts per pixel: 32 data + 8 pad (2-way bank spread, free)
#define ROWU  1536          // ushorts per ring slot (>= LCOLS*PXS = 1360)
#define NRING 16            // ring of 16 row slots; window is 10 rows
#define NI    10            // aligned float4 positions per halo row

typedef __attribute__((ext_vector_type(8))) short  short8;   // 8 bf16 = 4 VGPRs
typedef __attribute__((ext_vector_type(4))) float  floatx4;  // MFMA C/D + vec loads/stores

// fp32 -> bf16, round-to-nearest-even
__device__ __forceinline__ unsigned short f2bf(float f) {
    unsigned int u = __float_as_uint(f);
    u += 0x7FFFu + ((u >> 16) & 1u);
    return (unsigned short)(u >> 16);
}

// ---------------------------------------------------------------------------
// Mix expert weights per sample -> bf16, layout [b][co][k = tap*32 + ci].
// ---------------------------------------------------------------------------
__global__ __launch_bounds__(256) void prep_weights(
    const float* __restrict__ routing,   // [16][8]
    const float* __restrict__ ew,        // [8][9216]
    const float* __restrict__ eb,        // [8][32]
    unsigned short* __restrict__ ws_w,   // [16][32][288] bf16 bits
    float* __restrict__ ws_b)            // [16][32]
{
    const int b = blockIdx.x;
    const int t = threadIdx.x;
    float r[NE];
#pragma unroll
    for (int e = 0; e < NE; ++e) r[e] = routing[b * NE + e];

    for (int idx = t; idx < COUT * KTOT; idx += 256) {
        const int co  = idx / KTOT;
        const int k   = idx - co * KTOT;
        const int tap = k >> 5;
        const int ci  = k & 31;
        float acc = 0.f;
#pragma unroll
        for (int e = 0; e < NE; ++e)
            acc += r[e] * ew[e * (COUT * CIN * 9) + co * (CIN * 9) + ci * 9 + tap];
        ws_w[(b * COUT + co) * KTOT + k] = f2bf(acc);
    }
    if (t < COUT) {
        float acc = 0.f;
#pragma unroll
        for (int e = 0; e < NE; ++e) acc += r[e] * eb[e * COUT + t];
        ws_b[b * COUT + t] = acc;
    }
}

// ---------------------------------------------------------------------------
// Persistent y-walk implicit-GEMM conv, software-pipelined (T14 async-split):
// block owns a 32-wide x-strip and walks 8 y-tiles (8 rows each) through a
// 16-slot LDS row ring. Per step: issue next 8 halo rows' global loads EARLY
// (sched_barrier keeps them above compute), compute current tile (zero vmem
// reads: all 9 taps' weight frags preloaded), store, barrier (= the vmcnt
// drain, placed exactly where load data is needed), cvt+ds_write, barrier.
// HBM stays busy during every compute phase -> breaks the phase-locked-convoy
// plateau at ~3 TB/s. y-walk also reuses halo rows (fetch 1.56x -> 1.29x).
// ---------------------------------------------------------------------------
__global__ __launch_bounds__(256, 2) void condconv_mfma(
    const float* __restrict__ x,             // [16][32][256][256] fp32
    const unsigned short* __restrict__ wsw,  // [16][32][288] bf16
    const float* __restrict__ wsb,           // [16][32]
    float* __restrict__ out)                 // [16][32][256][256] fp32
{
    __shared__ __align__(16) unsigned short s_x[NRING * ROWU];  // 49,152 B

    const int b    = blockIdx.z;
    const int x0   = blockIdx.x * TW;
    const int ych  = blockIdx.y * CHROWS;
    const int t    = threadIdx.x;
    const int lane = t & 63;
    const int wv   = t >> 6;        // wave 0..3
    const int ln   = lane & 15;     // A-row pixel on LDS reads; co on output
    const int quad = lane >> 4;     // k-group / D-row group

    // ---- preload ALL 9 taps' weight fragments (72 VGPR) + bias ----
    // Chunk-invariant; keeps the compute phase free of vmem reads so the
    // staged loads stay in flight until the post-compute barrier.
    const unsigned short* wb = wsw + (size_t)b * COUT * KTOT;
    short8 wf0[NTAP], wf1[NTAP];
#pragma unroll
    for (int tap = 0; tap < NTAP; ++tap) {
        wf0[tap] = *(const short8*)(wb + ln * KTOT + tap * 32 + quad * 8);
        wf1[tap] = *(const short8*)(wb + (16 + ln) * KTOT + tap * 32 + quad * 8);
    }
    const float bias0 = wsb[b * COUT + ln];
    const float bias1 = wsb[b * COUT + 16 + ln];

    // ---- prologue: stage rows gy in [ych-1, ych+8] (10 rows) ----
    for (int task = t; task < 10 * NI * 4; task += 256) {
        const int cg  = task & 3;
        const int ri  = task >> 2;
        const int i   = ri % NI;
        const int row = ri / NI;          // 0..9
        const int gy  = ych - 1 + row;
        const int gx  = x0 + 4 * i - 4;
        floatx4 v[8];
        if (gy >= 0 && gy < HH && gx >= 0 && gx < WW) {
            const float* src = x + (((size_t)b * CIN + cg * 8) * HH + gy) * WW + gx;
#pragma unroll
            for (int u = 0; u < 8; ++u)
                v[u] = *(const floatx4*)(src + (size_t)u * HH * WW);
        } else {
#pragma unroll
            for (int u = 0; u < 8; ++u) v[u] = (floatx4){0.f, 0.f, 0.f, 0.f};
        }
        const int slot = (gy + 1) & (NRING - 1);
#pragma unroll
        for (int j = 0; j < 4; ++j) {
            const int lcol = 4 * i + j - 3;
            if (lcol >= 0 && lcol < LCOLS) {
                short8 pk;
#pragma unroll
                for (int u = 0; u < 8; ++u) pk[u] = (short)f2bf(v[u][j]);
                *(short8*)&s_x[slot * ROWU + lcol * PXS + cg * 8] = pk;
            }
        }
    }

    // ---- persistent staging-slot decode (8 new rows = 320 tasks/step) ----
    // slot0: task t (all threads). slot1: task 256+t (wave 0 only).
    const int cg0  = t & 3;
    const int ri0  = t >> 2;           // 0..63
    const int i0   = ri0 % NI;
    const int rn0  = ri0 / NI;         // 0..6
    const int gx0  = x0 + 4 * i0 - 4;
    const bool xok0 = (gx0 >= 0 && gx0 < WW);
    const int ri1  = 64 + ri0;         // 64..79 (wave 0 lanes)
    const int i1   = ri1 % NI;
    const int rn1  = ri1 / NI;         // 6..7
    const int gx1  = x0 + 4 * i1 - 4;
    const bool xok1 = (gx1 >= 0 && gx1 < WW);

    int cpart[4];
#pragma unroll
    for (int tt = 0; tt < 4; ++tt)
        cpart[tt] = ((tt & 1) * 16 + ln) * PXS + quad * 8;

    int rb   = ych & (NRING - 1);              // ring base of input row y0k-1's +1
    int swr0 = (ych + 10 + rn0) & (NRING - 1); // write slot for slot0
    int swr1 = (ych + 10 + rn1) & (NRING - 1); // write slot for slot1

    __syncthreads();

    // ---- main y-walk: 8 steps ----
#pragma unroll 1
    for (int k = 0; k < NSTEP; ++k) {
        const int y0k  = ych + 8 * k;
        const bool last = (k == NSTEP - 1);

        // 1) issue next step's halo-row loads (stay above compute)
        floatx4 v0[8], v1[8];
        if (!last) {
            const int gyn0 = y0k + 9 + rn0;
            if (xok0 && gyn0 < HH) {
                const float* s0 = x + (((size_t)b * CIN + cg0 * 8) * HH + gyn0) * WW + gx0;
#pragma unroll
                for (int u = 0; u < 8; ++u)
                    v0[u] = *(const floatx4*)(s0 + (size_t)u * HH * WW);
            } else {
#pragma unroll
                for (int u = 0; u < 8; ++u) v0[u] = (floatx4){0.f, 0.f, 0.f, 0.f};
            }
            if (wv == 0) {
                const int gyn1 = y0k + 9 + rn1;
                if (xok1 && gyn1 < HH) {
                    const float* s1 = x + (((size_t)b * CIN + cg0 * 8) * HH + gyn1) * WW + gx1;
#pragma unroll
                    for (int u = 0; u < 8; ++u)
                        v1[u] = *(const floatx4*)(s1 + (size_t)u * HH * WW);
                } else {
#pragma unroll
                    for (int u = 0; u < 8; ++u) v1[u] = (floatx4){0.f, 0.f, 0.f, 0.f};
                }
            }
        }
        __builtin_amdgcn_sched_barrier(0);   // pin load issue above compute

        // 2) compute current tile from the ring (LDS + MFMA only)
        floatx4 acc[4][2];
#pragma unroll
        for (int tt = 0; tt < 4; ++tt) {
            acc[tt][0] = (floatx4){0.f, 0.f, 0.f, 0.f};
            acc[tt][1] = (floatx4){0.f, 0.f, 0.f, 0.f};
        }
#pragma unroll
        for (int tap = 0; tap < NTAP; ++tap) {
            const int dy = tap / 3;
            const int dx = tap - dy * 3;
            int so[2];
#pragma unroll
            for (int rg = 0; rg < 2; ++rg)
                so[rg] = ((rb + 2 * wv + rg + dy) & (NRING - 1)) * ROWU + dx * PXS;
#pragma unroll
            for (int tt = 0; tt < 4; ++tt) {
                const short8 pfr = *(const short8*)&s_x[so[tt >> 1] + cpart[tt]];
                acc[tt][0] = __builtin_amdgcn_mfma_f32_16x16x32_bf16(pfr, wf0[tap], acc[tt][0], 0, 0, 0);
                acc[tt][1] = __builtin_amdgcn_mfma_f32_16x16x32_bf16(pfr, wf1[tap], acc[tt][1], 0, 0, 0);
            }
        }

        // 3) store tile (vector dwordx4; D rows = 4 consecutive x-pixels/lane)
#pragma unroll
        for (int tt = 0; tt < 4; ++tt) {
            const int gy = y0k + 2 * wv + (tt >> 1);
            const int gx = x0 + (tt & 1) * 16 + quad * 4;
            floatx4 o0 = acc[tt][0];
            floatx4 o1 = acc[tt][1];
#pragma unroll
            for (int e = 0; e < 4; ++e) { o0[e] += bias0; o1[e] += bias1; }
            *(floatx4*)(out + (((size_t)b * COUT + ln)      * HH + gy) * WW + gx) = o0;
            *(floatx4*)(out + (((size_t)b * COUT + 16 + ln) * HH + gy) * WW + gx) = o1;
        }

        // 4) rotate ring: drain (at barrier), convert, write new rows
        if (!last) {
            __syncthreads();   // all reads of window k done; drains staged loads
#pragma unroll
            for (int j = 0; j < 4; ++j) {
                const int lcol = 4 * i0 + j - 3;
                if (lcol >= 0 && lcol < LCOLS) {
                    short8 pk;
#pragma unroll
                    for (int u = 0; u < 8; ++u) pk[u] = (short)f2bf(v0[u][j]);
                    *(short8*)&s_x[swr0 * ROWU + lcol * PXS + cg0 * 8] = pk;
                }
            }
            if (wv == 0) {
#pragma unroll
                for (int j = 0; j < 4; ++j) {
                    const int lcol = 4 * i1 + j - 3;
                    if (lcol >= 0 && lcol < LCOLS) {
                        short8 pk;
#pragma unroll
                        for (int u = 0; u < 8; ++u) pk[u] = (short)f2bf(v1[u][j]);
                        *(short8*)&s_x[swr1 * ROWU + lcol * PXS + cg0 * 8] = pk;
                    }
                }
            }
            __syncthreads();   // window k+1 valid
            rb   = (rb + 8)   & (NRING - 1);
            swr0 = (swr0 + 8) & (NRING - 1);
            swr1 = (swr1 + 8) & (NRING - 1);
        }
    }
}

extern "C" void kernel_launch(void* const* d_in, const int* in_sizes, int n_in,
                              void* d_out, int out_size, void* d_ws, size_t ws_size,
                              hipStream_t stream) {
    const float* x       = (const float*)d_in[0];
    const float* routing = (const float*)d_in[1];
    const float* ew      = (const float*)d_in[2];
    const float* eb      = (const float*)d_in[3];
    float* out = (float*)d_out;

    unsigned short* ws_w = (unsigned short*)d_ws;            // 16*32*288 bf16 = 294912 B
    float* ws_b = (float*)((char*)d_ws + (size_t)B_ * COUT * KTOT * 2);

    prep_weights<<<dim3(B_), dim3(256), 0, stream>>>(routing, ew, eb, ws_w, ws_b);

    dim3 grid(WW / TW, HH / CHROWS, B_);                     // (8, 4, 16) = 512 blocks
    condconv_mfma<<<grid, dim3(256), 0, stream>>>(x, ws_w, ws_b, out);
}

// Round 6
// 287.501 us; speedup vs baseline: 1.0303x; 1.0303x over previous
//
#include <hip/hip_runtime.h>

#define B_   16
#define CIN  32
#define COUT 32
#define HH   256
#define WW   256
#define NE   8
#define NTAP 9
#define KTOT (NTAP * CIN)   // 288

#define CHROWS 16           // output rows per block (y-chunk)
#define NSTEP  8            // 2 rows per step
#define NRING  6            // LDS ring slots (full input rows)
#define PXS    40           // ushorts per pixel: 32 data + 8 pad (bank spread)
#define SLOTU  (258 * PXS)  // ushorts per ring slot (px-index 0..257 = px -1..256)

typedef __attribute__((ext_vector_type(8))) short  short8;   // 8 bf16 = 4 VGPRs
typedef __attribute__((ext_vector_type(4))) float  floatx4;  // MFMA C/D + vec loads/stores

// fp32 -> bf16, round-to-nearest-even
__device__ __forceinline__ unsigned short f2bf(float f) {
    unsigned int u = __float_as_uint(f);
    u += 0x7FFFu + ((u >> 16) & 1u);
    return (unsigned short)(u >> 16);
}

// ---------------------------------------------------------------------------
// Mix expert weights per sample -> bf16, layout [b][co][k = tap*32 + ci].
// ---------------------------------------------------------------------------
__global__ __launch_bounds__(256) void prep_weights(
    const float* __restrict__ routing,   // [16][8]
    const float* __restrict__ ew,        // [8][9216]
    const float* __restrict__ eb,        // [8][32]
    unsigned short* __restrict__ ws_w,   // [16][32][288] bf16 bits
    float* __restrict__ ws_b)            // [16][32]
{
    const int b = blockIdx.x;
    const int t = threadIdx.x;
    float r[NE];
#pragma unroll
    for (int e = 0; e < NE; ++e) r[e] = routing[b * NE + e];

    for (int idx = t; idx < COUT * KTOT; idx += 256) {
        const int co  = idx / KTOT;
        const int k   = idx - co * KTOT;
        const int tap = k >> 5;
        const int ci  = k & 31;
        float acc = 0.f;
#pragma unroll
        for (int e = 0; e < NE; ++e)
            acc += r[e] * ew[e * (COUT * CIN * 9) + co * (CIN * 9) + ci * 9 + tap];
        ws_w[(b * COUT + co) * KTOT + k] = f2bf(acc);
    }
    if (t < COUT) {
        float acc = 0.f;
#pragma unroll
        for (int e = 0; e < NE; ++e) acc += r[e] * eb[e * COUT + t];
        ws_b[b * COUT + t] = acc;
    }
}

// ---------------------------------------------------------------------------
// FULL-ROW persistent conv: block = (b, 16-row y-chunk), 512 thr (8 waves),
// walks 2 output rows/step through a 6-slot full-row LDS ring (124 KB).
// DRAM-pattern thesis: per (block, plane) streams are now FULLY SEQUENTIAL
// (1 KB/row contiguous, rows consecutive) on both read and write sides,
// instead of 128-256 B chunks with 1 KB holes -> page-hit efficiency.
// x-halo px -1/256 are out-of-image zeros -> permanently-zeroed LDS columns,
// so gross fetch = 128 MB * 18/16 only. R5's async-split pipeline retained:
// issue next 2 rows' loads early (sched_barrier), compute (zero vmem reads:
// all 9 taps' weight frags preloaded), store, barrier(=drain), cvt+ds_write.
// ---------------------------------------------------------------------------
__global__ __launch_bounds__(512, 2) void condconv_mfma(
    const float* __restrict__ x,             // [16][32][256][256] fp32
    const unsigned short* __restrict__ wsw,  // [16][32][288] bf16
    const float* __restrict__ wsb,           // [16][32]
    float* __restrict__ out)                 // [16][32][256][256] fp32
{
    __shared__ __align__(16) unsigned short s_x[NRING * SLOTU];  // 123,840 B

    const int b    = blockIdx.z;
    const int y0   = blockIdx.y * CHROWS;
    const int t    = threadIdx.x;
    const int lane = t & 63;
    const int wv   = t >> 6;        // wave 0..7
    const int ln   = lane & 15;     // A-row pixel on LDS reads; co on output
    const int quad = lane >> 4;     // k-group / D-row group

    // ---- preload ALL 9 taps' weight fragments (72 VGPR) + bias ----
    const unsigned short* wb = wsw + (size_t)b * COUT * KTOT;
    short8 wf0[NTAP], wf1[NTAP];
#pragma unroll
    for (int tap = 0; tap < NTAP; ++tap) {
        wf0[tap] = *(const short8*)(wb + ln * KTOT + tap * 32 + quad * 8);
        wf1[tap] = *(const short8*)(wb + (16 + ln) * KTOT + tap * 32 + quad * 8);
    }
    const float bias0 = wsb[b * COUT + ln];
    const float bias1 = wsb[b * COUT + 16 + ln];

    // ---- zero the two x-halo columns (px-index 0 and 257) of all slots ----
    if (t < 48) {
        const int slot = t >> 3;          // 0..5
        const int rest = t & 7;
        const int col  = (rest >> 2) ? 257 : 0;
        const int cg   = rest & 3;
        *(short8*)&s_x[slot * SLOTU + col * PXS + cg * 8] =
            (short8){0, 0, 0, 0, 0, 0, 0, 0};
    }

    // ---- prologue: stage input rows y0-1 .. y0+2 (4 full rows) ----
    for (int task = t; task < 4 * 64 * 4; task += 512) {
        const int cg  = task & 3;
        const int i4  = (task >> 2) & 63;
        const int row = task >> 8;        // 0..3
        const int gy  = y0 - 1 + row;
        const int gx  = i4 * 4;           // 0..252, 16B-aligned
        floatx4 v[8];
        if (gy >= 0 && gy < HH) {
            const float* src = x + (((size_t)b * CIN + cg * 8) * HH + gy) * WW + gx;
#pragma unroll
            for (int u = 0; u < 8; ++u)
                v[u] = *(const floatx4*)(src + (size_t)u * HH * WW);
        } else {
#pragma unroll
            for (int u = 0; u < 8; ++u) v[u] = (floatx4){0.f, 0.f, 0.f, 0.f};
        }
        const int slot = (gy + 1) % NRING;   // gy+1 >= 0
#pragma unroll
        for (int j = 0; j < 4; ++j) {
            short8 pk;
#pragma unroll
            for (int u = 0; u < 8; ++u) pk[u] = (short)f2bf(v[u][j]);
            *(short8*)&s_x[slot * SLOTU + (gx + j + 1) * PXS + cg * 8] = pk;
        }
    }

    // persistent staging decode: 1 task/thread/step = (row01, i4, cg)
    const int cg0  = t & 3;
    const int i40  = (t >> 2) & 63;
    const int rw0  = (t >> 8) & 1;        // 0..1
    const int gx0  = i40 * 4;

    const int r    = wv >> 2;             // output row within step: 0..1
    const int xs0  = (wv & 3) * 4;        // xsub base: wave owns xsub xs0..xs0+3

    int rb = y0 % NRING;                  // ring slot of input row y0k-1

    __syncthreads();

    // ---- main y-walk: 8 steps of 2 rows ----
#pragma unroll 1
    for (int k = 0; k < NSTEP; ++k) {
        const int y0k  = y0 + 2 * k;
        const bool last = (k == NSTEP - 1);
        const int gyn  = y0k + 3 + rw0;   // next window's new input row

        // 1) issue next rows' loads (pinned above compute)
        floatx4 v[8];
        if (!last) {
            if (gyn < HH) {
                const float* src = x + (((size_t)b * CIN + cg0 * 8) * HH + gyn) * WW + gx0;
#pragma unroll
                for (int u = 0; u < 8; ++u)
                    v[u] = *(const floatx4*)(src + (size_t)u * HH * WW);
            } else {
#pragma unroll
                for (int u = 0; u < 8; ++u) v[u] = (floatx4){0.f, 0.f, 0.f, 0.f};
            }
        }
        __builtin_amdgcn_sched_barrier(0);

        // 2) compute 2 output rows x 256 px from the ring (LDS + MFMA only)
        floatx4 acc[4][2];
#pragma unroll
        for (int n = 0; n < 4; ++n) {
            acc[n][0] = (floatx4){0.f, 0.f, 0.f, 0.f};
            acc[n][1] = (floatx4){0.f, 0.f, 0.f, 0.f};
        }
#pragma unroll
        for (int tap = 0; tap < NTAP; ++tap) {
            const int dy = tap / 3;
            const int dx = tap - dy * 3;
            int slot = rb + r + dy;                   // input row y0k-1 + (r+dy)
            slot -= (slot >= NRING) ? NRING : 0;
            const int sb = slot * SLOTU;
#pragma unroll
            for (int n = 0; n < 4; ++n) {
                const short8 pfr =
                    *(const short8*)&s_x[sb + ((xs0 + n) * 16 + ln + dx) * PXS + quad * 8];
                acc[n][0] = __builtin_amdgcn_mfma_f32_16x16x32_bf16(pfr, wf0[tap], acc[n][0], 0, 0, 0);
                acc[n][1] = __builtin_amdgcn_mfma_f32_16x16x32_bf16(pfr, wf1[tap], acc[n][1], 0, 0, 0);
            }
        }

        // 3) store (D rows = 4 consecutive x-px/lane -> dwordx4; sequential per co-plane)
        const int gy = y0k + r;
#pragma unroll
        for (int n = 0; n < 4; ++n) {
            const int gx = (xs0 + n) * 16 + quad * 4;
            floatx4 o0 = acc[n][0];
            floatx4 o1 = acc[n][1];
#pragma unroll
            for (int e = 0; e < 4; ++e) { o0[e] += bias0; o1[e] += bias1; }
            *(floatx4*)(out + (((size_t)b * COUT + ln)      * HH + gy) * WW + gx) = o0;
            *(floatx4*)(out + (((size_t)b * COUT + 16 + ln) * HH + gy) * WW + gx) = o1;
        }

        // 4) rotate ring: drain at barrier, convert, write 2 new rows
        if (!last) {
            __syncthreads();   // window-k reads done; drains staged loads
            int slotw = rb + 4 + rw0;                 // slot of row gyn
            slotw -= (slotw >= NRING) ? NRING : 0;
#pragma unroll
            for (int j = 0; j < 4; ++j) {
                short8 pk;
#pragma unroll
                for (int u = 0; u < 8; ++u) pk[u] = (short)f2bf(v[u][j]);
                *(short8*)&s_x[slotw * SLOTU + (gx0 + j + 1) * PXS + cg0 * 8] = pk;
            }
            __syncthreads();   // window k+1 valid
            rb += 2;
            rb -= (rb >= NRING) ? NRING : 0;
        }
    }
}

extern "C" void kernel_launch(void* const* d_in, const int* in_sizes, int n_in,
                              void* d_out, int out_size, void* d_ws, size_t ws_size,
                              hipStream_t stream) {
    const float* x       = (const float*)d_in[0];
    const float* routing = (const float*)d_in[1];
    const float* ew      = (const float*)d_in[2];
    const float* eb      = (const float*)d_in[3];
    float* out = (float*)d_out;

    unsigned short* ws_w = (unsigned short*)d_ws;            // 16*32*288 bf16 = 294912 B
    float* ws_b = (float*)((char*)d_ws + (size_t)B_ * COUT * KTOT * 2);

    prep_weights<<<dim3(B_), dim3(256), 0, stream>>>(routing, ew, eb, ws_w, ws_b);

    dim3 grid(1, HH / CHROWS, B_);                           // (1, 16, 16) = 256 blocks
    condconv_mfma<<<grid, dim3(512), 0, stream>>>(x, ws_w, ws_b, out);
}

// Round 7
// 279.674 us; speedup vs baseline: 1.0592x; 1.0280x over previous
//
#include <hip/hip_runtime.h>

#define B_   16
#define CIN  32
#define COUT 32
#define HH   256
#define WW   256
#define NE   8
#define NTAP 9
#define KTOT (NTAP * CIN)   // 288

#define CHROWS 16           // output rows per block (y-chunk)
#define NSTEP  8            // 2 rows per step
#define NRING  6            // LDS ring slots (full input rows)
#define PXS    40           // ushorts per pixel: 32 data + 8 pad (bank spread)
#define SLOTU  (258 * PXS)  // ushorts per ring slot (px-index 0..257 = px -1..256)
#define OSTR   264          // floats per co-row in the store-transpose buffer

typedef __attribute__((ext_vector_type(8))) short  short8;   // 8 bf16 = 4 VGPRs
typedef __attribute__((ext_vector_type(4))) float  floatx4;  // MFMA C/D + vec loads/stores

// fp32 -> bf16, round-to-nearest-even
__device__ __forceinline__ unsigned short f2bf(float f) {
    unsigned int u = __float_as_uint(f);
    u += 0x7FFFu + ((u >> 16) & 1u);
    return (unsigned short)(u >> 16);
}

// Raw workgroup barrier that does NOT drain vmcnt: LDS ordering only.
// Stores stay in flight across it (the whole point — no per-step store drain).
__device__ __forceinline__ void bar_lgkm() {
    asm volatile("s_waitcnt lgkmcnt(0)" ::: "memory");
    __builtin_amdgcn_sched_barrier(0);
    __builtin_amdgcn_s_barrier();
    __builtin_amdgcn_sched_barrier(0);
}

// ---------------------------------------------------------------------------
// Mix expert weights per sample -> bf16, layout [b][co][k = tap*32 + ci].
// ---------------------------------------------------------------------------
__global__ __launch_bounds__(256) void prep_weights(
    const float* __restrict__ routing,   // [16][8]
    const float* __restrict__ ew,        // [8][9216]
    const float* __restrict__ eb,        // [8][32]
    unsigned short* __restrict__ ws_w,   // [16][32][288] bf16 bits
    float* __restrict__ ws_b)            // [16][32]
{
    const int b = blockIdx.x;
    const int t = threadIdx.x;
    float r[NE];
#pragma unroll
    for (int e = 0; e < NE; ++e) r[e] = routing[b * NE + e];

    for (int idx = t; idx < COUT * KTOT; idx += 256) {
        const int co  = idx / KTOT;
        const int k   = idx - co * KTOT;
        const int tap = k >> 5;
        const int ci  = k & 31;
        float acc = 0.f;
#pragma unroll
        for (int e = 0; e < NE; ++e)
            acc += r[e] * ew[e * (COUT * CIN * 9) + co * (CIN * 9) + ci * 9 + tap];
        ws_w[(b * COUT + co) * KTOT + k] = f2bf(acc);
    }
    if (t < COUT) {
        float acc = 0.f;
#pragma unroll
        for (int e = 0; e < NE; ++e) acc += r[e] * eb[e * COUT + t];
        ws_b[b * COUT + t] = acc;
    }
}

// ---------------------------------------------------------------------------
// FULL-ROW persistent conv (R6 structure) + write-path fix:
//  * epilogue transposes the 2-row output tile through LDS so each wave
//    stores 1 KB fully-contiguous per co-plane-row (64 lanes x dwordx4,
//    lane-sequential) instead of 64 B chunks scattered over 16 planes;
//  * all in-loop barriers are lgkmcnt-only (raw s_barrier) — stores are
//    never vmcnt-drained inside the loop, they retire asynchronously.
// Ring: read slots rb..rb+3 vs write slots rb+4..rb+5 are disjoint, so a
// single end-of-step barrier covers the rotation.
// ---------------------------------------------------------------------------
__global__ __launch_bounds__(512, 2) void condconv_mfma(
    const float* __restrict__ x,             // [16][32][256][256] fp32
    const unsigned short* __restrict__ wsw,  // [16][32][288] bf16
    const float* __restrict__ wsb,           // [16][32]
    float* __restrict__ out)                 // [16][32][256][256] fp32
{
    __shared__ __align__(16) unsigned short s_x[NRING * SLOTU];  // 123,840 B
    __shared__ __align__(16) float s_o[2 * 16 * OSTR];           //  33,792 B

    const int b    = blockIdx.z;
    const int y0   = blockIdx.y * CHROWS;
    const int t    = threadIdx.x;
    const int lane = t & 63;
    const int wv   = t >> 6;        // wave 0..7
    const int ln   = lane & 15;     // A-row pixel on LDS reads; co on D
    const int quad = lane >> 4;     // k-group / D-row group

    // ---- preload ALL 9 taps' weight fragments (72 VGPR) + bias ----
    const unsigned short* wb = wsw + (size_t)b * COUT * KTOT;
    short8 wf0[NTAP], wf1[NTAP];
#pragma unroll
    for (int tap = 0; tap < NTAP; ++tap) {
        wf0[tap] = *(const short8*)(wb + ln * KTOT + tap * 32 + quad * 8);
        wf1[tap] = *(const short8*)(wb + (16 + ln) * KTOT + tap * 32 + quad * 8);
    }
    const float bias0 = wsb[b * COUT + ln];
    const float bias1 = wsb[b * COUT + 16 + ln];

    // ---- zero the two x-halo columns (px-index 0 and 257) of all slots ----
    if (t < 48) {
        const int slot = t >> 3;          // 0..5
        const int rest = t & 7;
        const int col  = (rest >> 2) ? 257 : 0;
        const int cg   = rest & 3;
        *(short8*)&s_x[slot * SLOTU + col * PXS + cg * 8] =
            (short8){0, 0, 0, 0, 0, 0, 0, 0};
    }

    // ---- prologue: stage input rows y0-1 .. y0+2 (4 full rows) ----
    for (int task = t; task < 4 * 64 * 4; task += 512) {
        const int cg  = task & 3;
        const int i4  = (task >> 2) & 63;
        const int row = task >> 8;        // 0..3
        const int gy  = y0 - 1 + row;
        const int gx  = i4 * 4;           // 0..252, 16B-aligned
        floatx4 v[8];
        if (gy >= 0 && gy < HH) {
            const float* src = x + (((size_t)b * CIN + cg * 8) * HH + gy) * WW + gx;
#pragma unroll
            for (int u = 0; u < 8; ++u)
                v[u] = *(const floatx4*)(src + (size_t)u * HH * WW);
        } else {
#pragma unroll
            for (int u = 0; u < 8; ++u) v[u] = (floatx4){0.f, 0.f, 0.f, 0.f};
        }
        const int slot = (gy + 1) % NRING;   // gy+1 >= 0
#pragma unroll
        for (int j = 0; j < 4; ++j) {
            short8 pk;
#pragma unroll
            for (int u = 0; u < 8; ++u) pk[u] = (short)f2bf(v[u][j]);
            *(short8*)&s_x[slot * SLOTU + (gx + j + 1) * PXS + cg * 8] = pk;
        }
    }

    // persistent staging decode: 1 task/thread/step = (row01, i4, cg)
    const int cg0  = t & 3;
    const int i40  = (t >> 2) & 63;
    const int rw0  = (t >> 8) & 1;        // 0..1
    const int gx0  = i40 * 4;

    const int r    = wv >> 2;             // output row within step: 0..1
    const int xs0  = (wv & 3) * 4;        // xsub base: wave owns xsub xs0..xs0+3
    const int co4  = (wv & 3) * 4;        // pass-B: 4 co-planes per wave

    int rb = y0 % NRING;                  // ring slot of input row y0k-1

    __syncthreads();

    // ---- main y-walk: 8 steps of 2 rows ----
#pragma unroll 1
    for (int k = 0; k < NSTEP; ++k) {
        const int y0k  = y0 + 2 * k;
        const bool last = (k == NSTEP - 1);
        const int gyn  = y0k + 3 + rw0;   // next window's new input row

        // 1) issue next rows' loads (pinned above compute)
        floatx4 v[8];
        if (!last) {
            if (gyn < HH) {
                const float* src = x + (((size_t)b * CIN + cg0 * 8) * HH + gyn) * WW + gx0;
#pragma unroll
                for (int u = 0; u < 8; ++u)
                    v[u] = *(const floatx4*)(src + (size_t)u * HH * WW);
            } else {
#pragma unroll
                for (int u = 0; u < 8; ++u) v[u] = (floatx4){0.f, 0.f, 0.f, 0.f};
            }
        }
        __builtin_amdgcn_sched_barrier(0);

        // 2) compute 2 output rows x 256 px from the ring (LDS + MFMA only)
        floatx4 acc[4][2];
#pragma unroll
        for (int n = 0; n < 4; ++n) {
            acc[n][0] = (floatx4){0.f, 0.f, 0.f, 0.f};
            acc[n][1] = (floatx4){0.f, 0.f, 0.f, 0.f};
        }
#pragma unroll
        for (int tap = 0; tap < NTAP; ++tap) {
            const int dy = tap / 3;
            const int dx = tap - dy * 3;
            int slot = rb + r + dy;                   // input row y0k-1 + (r+dy)
            slot -= (slot >= NRING) ? NRING : 0;
            const int sb = slot * SLOTU;
#pragma unroll
            for (int n = 0; n < 4; ++n) {
                const short8 pfr =
                    *(const short8*)&s_x[sb + ((xs0 + n) * 16 + ln + dx) * PXS + quad * 8];
                acc[n][0] = __builtin_amdgcn_mfma_f32_16x16x32_bf16(pfr, wf0[tap], acc[n][0], 0, 0, 0);
                acc[n][1] = __builtin_amdgcn_mfma_f32_16x16x32_bf16(pfr, wf1[tap], acc[n][1], 0, 0, 0);
            }
        }

        // 3) epilogue: LDS-transpose, then wave-contiguous 1 KB stores.
        //    Two passes (co-half h); buf holds [row 0..1][co16 0..15][px].
#pragma unroll
        for (int h = 0; h < 2; ++h) {
            const float bs = h ? bias1 : bias0;
            // pass A: scatter acc into buf (this wave's row r, co = ln)
#pragma unroll
            for (int n = 0; n < 4; ++n) {
                floatx4 o = acc[n][h];
#pragma unroll
                for (int e = 0; e < 4; ++e) o[e] += bs;
                *(floatx4*)&s_o[(r * 16 + ln) * OSTR + (xs0 + n) * 16 + quad * 4] = o;
            }
            bar_lgkm();
            // pass B: each wave stores 4 full co-plane rows, 1 KB contiguous each
#pragma unroll
            for (int j = 0; j < 4; ++j) {
                const int co16 = co4 + j;
                const floatx4 o = *(const floatx4*)&s_o[(r * 16 + co16) * OSTR + lane * 4];
                *(floatx4*)(out + (((size_t)b * COUT + h * 16 + co16) * HH + (y0k + r)) * WW + lane * 4) = o;
            }
            bar_lgkm();   // buf reads done before next pass-A overwrite
        }

        // 4) rotate ring: convert + write 2 new rows (slots rb+4, rb+5 — disjoint
        //    from this window's read slots rb..rb+3), one lgkm-barrier, advance.
        if (!last) {
            int slotw = rb + 4 + rw0;
            slotw -= (slotw >= NRING) ? NRING : 0;
#pragma unroll
            for (int j = 0; j < 4; ++j) {
                short8 pk;
#pragma unroll
                for (int u = 0; u < 8; ++u) pk[u] = (short)f2bf(v[u][j]);
                *(short8*)&s_x[slotw * SLOTU + (gx0 + j + 1) * PXS + cg0 * 8] = pk;
            }
            bar_lgkm();   // window k+1 valid (stores still in flight — by design)
            rb += 2;
            rb -= (rb >= NRING) ? NRING : 0;
        }
    }
}

extern "C" void kernel_launch(void* const* d_in, const int* in_sizes, int n_in,
                              void* d_out, int out_size, void* d_ws, size_t ws_size,
                              hipStream_t stream) {
    const float* x       = (const float*)d_in[0];
    const float* routing = (const float*)d_in[1];
    const float* ew      = (const float*)d_in[2];
    const float* eb      = (const float*)d_in[3];
    float* out = (float*)d_out;

    unsigned short* ws_w = (unsigned short*)d_ws;            // 16*32*288 bf16 = 294912 B
    float* ws_b = (float*)((char*)d_ws + (size_t)B_ * COUT * KTOT * 2);

    prep_weights<<<dim3(B_), dim3(256), 0, stream>>>(routing, ew, eb, ws_w, ws_b);

    dim3 grid(1, HH / CHROWS, B_);                           // (1, 16, 16) = 256 blocks
    condconv_mfma<<<grid, dim3(512), 0, stream>>>(x, ws_w, ws_b, out);
}

// Round 8
// 274.203 us; speedup vs baseline: 1.0803x; 1.0200x over previous
//
#include <hip/hip_runtime.h>

#define B_   16
#define CIN  32
#define COUT 32
#define HH   256
#define WW   256
#define NE   8
#define NTAP 9
#define KTOT (NTAP * CIN)   // 288

#define CHROWS 16           // output rows per block (y-chunk)
#define NSTEP  8            // 2 rows per step
#define NRING  6            // LDS ring slots (full input rows)
#define PXS    40           // ushorts per pixel: 32 data + 8 pad (bank spread)
#define SLOTU  (258 * PXS)  // ushorts per ring slot (px-index 0..257 = px -1..256)
#define OSTR   264          // floats per co-row in the store-transpose buffer

typedef __attribute__((ext_vector_type(8))) short  short8;   // 8 bf16 = 4 VGPRs
typedef __attribute__((ext_vector_type(4))) float  floatx4;  // MFMA C/D + vec loads/stores

// fp32 -> bf16, round-to-nearest-even
__device__ __forceinline__ unsigned short f2bf(float f) {
    unsigned int u = __float_as_uint(f);
    u += 0x7FFFu + ((u >> 16) & 1u);
    return (unsigned short)(u >> 16);
}

// Raw workgroup barrier that does NOT drain vmcnt: LDS ordering only.
// Stores stay in flight across it (no per-step store drain).
__device__ __forceinline__ void bar_lgkm() {
    asm volatile("s_waitcnt lgkmcnt(0)" ::: "memory");
    __builtin_amdgcn_sched_barrier(0);
    __builtin_amdgcn_s_barrier();
    __builtin_amdgcn_sched_barrier(0);
}

// ---------------------------------------------------------------------------
// Mix expert weights per sample -> bf16, layout [b][co][k = tap*32 + ci].
// ---------------------------------------------------------------------------
__global__ __launch_bounds__(256) void prep_weights(
    const float* __restrict__ routing,   // [16][8]
    const float* __restrict__ ew,        // [8][9216]
    const float* __restrict__ eb,        // [8][32]
    unsigned short* __restrict__ ws_w,   // [16][32][288] bf16 bits
    float* __restrict__ ws_b)            // [16][32]
{
    const int b = blockIdx.x;
    const int t = threadIdx.x;
    float r[NE];
#pragma unroll
    for (int e = 0; e < NE; ++e) r[e] = routing[b * NE + e];

    for (int idx = t; idx < COUT * KTOT; idx += 256) {
        const int co  = idx / KTOT;
        const int k   = idx - co * KTOT;
        const int tap = k >> 5;
        const int ci  = k & 31;
        float acc = 0.f;
#pragma unroll
        for (int e = 0; e < NE; ++e)
            acc += r[e] * ew[e * (COUT * CIN * 9) + co * (CIN * 9) + ci * 9 + tap];
        ws_w[(b * COUT + co) * KTOT + k] = f2bf(acc);
    }
    if (t < COUT) {
        float acc = 0.f;
#pragma unroll
        for (int e = 0; e < NE; ++e) acc += r[e] * eb[e * COUT + t];
        ws_b[b * COUT + t] = acc;
    }
}

// ---------------------------------------------------------------------------
// FULL-ROW persistent conv (R7 structure) + NON-TEMPORAL output stores.
// Theory: stores retire into L2/L3 and drain in eviction order (erasing
// in-kernel contiguity) while ALLOCATING in L3 — where they evict the
// 134 MB input (131+134 > 256 MB L3) -> schedule-invariant 1.44 TB/s write
// drain that paces every kernel variant so far. nt stores (no-allocate)
// (a) leave L3 to the input (fully resident -> FETCH ~0) and (b) stream
// 1 KB-contiguous wave-bursts to HBM in issue order (copy-ubench shape).
// Everything else identical to R7: lgkm-only barriers, zero vmem reads in
// compute (all 9 taps preloaded), LDS-transposed 1 KB-contiguous epilogue.
// ---------------------------------------------------------------------------
__global__ __launch_bounds__(512, 2) void condconv_mfma(
    const float* __restrict__ x,             // [16][32][256][256] fp32
    const unsigned short* __restrict__ wsw,  // [16][32][288] bf16
    const float* __restrict__ wsb,           // [16][32]
    float* __restrict__ out)                 // [16][32][256][256] fp32
{
    __shared__ __align__(16) unsigned short s_x[NRING * SLOTU];  // 123,840 B
    __shared__ __align__(16) float s_o[2 * 16 * OSTR];           //  33,792 B

    const int b    = blockIdx.z;
    const int y0   = blockIdx.y * CHROWS;
    const int t    = threadIdx.x;
    const int lane = t & 63;
    const int wv   = t >> 6;        // wave 0..7
    const int ln   = lane & 15;     // A-row pixel on LDS reads; co on D
    const int quad = lane >> 4;     // k-group / D-row group

    // ---- preload ALL 9 taps' weight fragments (72 VGPR) + bias ----
    const unsigned short* wb = wsw + (size_t)b * COUT * KTOT;
    short8 wf0[NTAP], wf1[NTAP];
#pragma unroll
    for (int tap = 0; tap < NTAP; ++tap) {
        wf0[tap] = *(const short8*)(wb + ln * KTOT + tap * 32 + quad * 8);
        wf1[tap] = *(const short8*)(wb + (16 + ln) * KTOT + tap * 32 + quad * 8);
    }
    const float bias0 = wsb[b * COUT + ln];
    const float bias1 = wsb[b * COUT + 16 + ln];

    // ---- zero the two x-halo columns (px-index 0 and 257) of all slots ----
    if (t < 48) {
        const int slot = t >> 3;          // 0..5
        const int rest = t & 7;
        const int col  = (rest >> 2) ? 257 : 0;
        const int cg   = rest & 3;
        *(short8*)&s_x[slot * SLOTU + col * PXS + cg * 8] =
            (short8){0, 0, 0, 0, 0, 0, 0, 0};
    }

    // ---- prologue: stage input rows y0-1 .. y0+2 (4 full rows) ----
    for (int task = t; task < 4 * 64 * 4; task += 512) {
        const int cg  = task & 3;
        const int i4  = (task >> 2) & 63;
        const int row = task >> 8;        // 0..3
        const int gy  = y0 - 1 + row;
        const int gx  = i4 * 4;           // 0..252, 16B-aligned
        floatx4 v[8];
        if (gy >= 0 && gy < HH) {
            const float* src = x + (((size_t)b * CIN + cg * 8) * HH + gy) * WW + gx;
#pragma unroll
            for (int u = 0; u < 8; ++u)
                v[u] = *(const floatx4*)(src + (size_t)u * HH * WW);
        } else {
#pragma unroll
            for (int u = 0; u < 8; ++u) v[u] = (floatx4){0.f, 0.f, 0.f, 0.f};
        }
        const int slot = (gy + 1) % NRING;   // gy+1 >= 0
#pragma unroll
        for (int j = 0; j < 4; ++j) {
            short8 pk;
#pragma unroll
            for (int u = 0; u < 8; ++u) pk[u] = (short)f2bf(v[u][j]);
            *(short8*)&s_x[slot * SLOTU + (gx + j + 1) * PXS + cg * 8] = pk;
        }
    }

    // persistent staging decode: 1 task/thread/step = (row01, i4, cg)
    const int cg0  = t & 3;
    const int i40  = (t >> 2) & 63;
    const int rw0  = (t >> 8) & 1;        // 0..1
    const int gx0  = i40 * 4;

    const int r    = wv >> 2;             // output row within step: 0..1
    const int xs0  = (wv & 3) * 4;        // xsub base: wave owns xsub xs0..xs0+3
    const int co4  = (wv & 3) * 4;        // pass-B: 4 co-planes per wave

    int rb = y0 % NRING;                  // ring slot of input row y0k-1

    __syncthreads();

    // ---- main y-walk: 8 steps of 2 rows ----
#pragma unroll 1
    for (int k = 0; k < NSTEP; ++k) {
        const int y0k  = y0 + 2 * k;
        const bool last = (k == NSTEP - 1);
        const int gyn  = y0k + 3 + rw0;   // next window's new input row

        // 1) issue next rows' loads (pinned above compute)
        floatx4 v[8];
        if (!last) {
            if (gyn < HH) {
                const float* src = x + (((size_t)b * CIN + cg0 * 8) * HH + gyn) * WW + gx0;
#pragma unroll
                for (int u = 0; u < 8; ++u)
                    v[u] = *(const floatx4*)(src + (size_t)u * HH * WW);
            } else {
#pragma unroll
                for (int u = 0; u < 8; ++u) v[u] = (floatx4){0.f, 0.f, 0.f, 0.f};
            }
        }
        __builtin_amdgcn_sched_barrier(0);

        // 2) compute 2 output rows x 256 px from the ring (LDS + MFMA only)
        floatx4 acc[4][2];
#pragma unroll
        for (int n = 0; n < 4; ++n) {
            acc[n][0] = (floatx4){0.f, 0.f, 0.f, 0.f};
            acc[n][1] = (floatx4){0.f, 0.f, 0.f, 0.f};
        }
#pragma unroll
        for (int tap = 0; tap < NTAP; ++tap) {
            const int dy = tap / 3;
            const int dx = tap - dy * 3;
            int slot = rb + r + dy;                   // input row y0k-1 + (r+dy)
            slot -= (slot >= NRING) ? NRING : 0;
            const int sb = slot * SLOTU;
#pragma unroll
            for (int n = 0; n < 4; ++n) {
                const short8 pfr =
                    *(const short8*)&s_x[sb + ((xs0 + n) * 16 + ln + dx) * PXS + quad * 8];
                acc[n][0] = __builtin_amdgcn_mfma_f32_16x16x32_bf16(pfr, wf0[tap], acc[n][0], 0, 0, 0);
                acc[n][1] = __builtin_amdgcn_mfma_f32_16x16x32_bf16(pfr, wf1[tap], acc[n][1], 0, 0, 0);
            }
        }

        // 3) epilogue: LDS-transpose, then wave-contiguous 1 KB NT stores.
#pragma unroll
        for (int h = 0; h < 2; ++h) {
            const float bs = h ? bias1 : bias0;
            // pass A: scatter acc into buf (this wave's row r, co = ln)
#pragma unroll
            for (int n = 0; n < 4; ++n) {
                floatx4 o = acc[n][h];
#pragma unroll
                for (int e = 0; e < 4; ++e) o[e] += bs;
                *(floatx4*)&s_o[(r * 16 + ln) * OSTR + (xs0 + n) * 16 + quad * 4] = o;
            }
            bar_lgkm();
            // pass B: each wave stores 4 full co-plane rows, 1 KB contiguous,
            // NON-TEMPORAL: no L2/L3 allocate -> input stays L3-resident and
            // the DRAM write stream keeps issue-order contiguity.
#pragma unroll
            for (int j = 0; j < 4; ++j) {
                const int co16 = co4 + j;
                const floatx4 o = *(const floatx4*)&s_o[(r * 16 + co16) * OSTR + lane * 4];
                __builtin_nontemporal_store(
                    o, (floatx4*)(out + (((size_t)b * COUT + h * 16 + co16) * HH + (y0k + r)) * WW + lane * 4));
            }
            bar_lgkm();   // buf reads done before next pass-A overwrite
        }

        // 4) rotate ring: convert + write 2 new rows (slots rb+4, rb+5 — disjoint
        //    from this window's read slots rb..rb+3), one lgkm-barrier, advance.
        if (!last) {
            int slotw = rb + 4 + rw0;
            slotw -= (slotw >= NRING) ? NRING : 0;
#pragma unroll
            for (int j = 0; j < 4; ++j) {
                short8 pk;
#pragma unroll
                for (int u = 0; u < 8; ++u) pk[u] = (short)f2bf(v[u][j]);
                *(short8*)&s_x[slotw * SLOTU + (gx0 + j + 1) * PXS + cg0 * 8] = pk;
            }
            bar_lgkm();   // window k+1 valid (stores still in flight — by design)
            rb += 2;
            rb -= (rb >= NRING) ? NRING : 0;
        }
    }
}

extern "C" void kernel_launch(void* const* d_in, const int* in_sizes, int n_in,
                              void* d_out, int out_size, void* d_ws, size_t ws_size,
                              hipStream_t stream) {
    const float* x       = (const float*)d_in[0];
    const float* routing = (const float*)d_in[1];
    const float* ew      = (const float*)d_in[2];
    const float* eb      = (const float*)d_in[3];
    float* out = (float*)d_out;

    unsigned short* ws_w = (unsigned short*)d_ws;            // 16*32*288 bf16 = 294912 B
    float* ws_b = (float*)((char*)d_ws + (size_t)B_ * COUT * KTOT * 2);

    prep_weights<<<dim3(B_), dim3(256), 0, stream>>>(routing, ew, eb, ws_w, ws_b);

    dim3 grid(1, HH / CHROWS, B_);                           // (1, 16, 16) = 256 blocks
    condconv_mfma<<<grid, dim3(512), 0, stream>>>(x, ws_w, ws_b, out);
}